// Round 5
// baseline (72.810 us; speedup 1.0000x reference)
//
#include <hip/hip_runtime.h>
#include <hip/hip_bf16.h>

#define B_ 8
#define N_ 4096
#define M_ 4096
#define D_ 64
#define BNT (B_ * N_)   // 32768
#define BMT (B_ * M_)   // 32768
#define TA 64           // A band rows per block (fragments in registers)
#define TB 64           // B rows per iteration (registers, direct from global)
#define CHUNK_TILES 16  // iterations per block -> 1024-row B chunk
#define CHUNK_B (TB * CHUNK_TILES)        // 1024
#define MCHUNK (M_ / CHUNK_B)             // 4

typedef short bf16x8 __attribute__((ext_vector_type(8)));
typedef float f32x4 __attribute__((ext_vector_type(4)));

__device__ __forceinline__ unsigned short f2bf(float f) {
  __hip_bfloat16 h = __float2bfloat16(f);
  return *reinterpret_cast<unsigned short*>(&h);
}

// Order-preserving float -> uint key for atomicMin/atomicMax(unsigned),
// correct for negative floats too.
__device__ __forceinline__ unsigned fkey(float f) {
  unsigned b = __float_as_uint(f);
  return b ^ ((unsigned)((int)b >> 31) | 0x80000000u);
}
__device__ __forceinline__ float funkey(unsigned k) {
  unsigned b = (k & 0x80000000u) ? (k ^ 0x80000000u) : ~k;
  return __uint_as_float(b);
}

__device__ __forceinline__ bf16x8 cvt8(float4 lo, float4 hi) {
  union { unsigned short u[8]; bf16x8 v; } r;
  r.u[0] = f2bf(lo.x); r.u[1] = f2bf(lo.y); r.u[2] = f2bf(lo.z); r.u[3] = f2bf(lo.w);
  r.u[4] = f2bf(hi.x); r.u[5] = f2bf(hi.y); r.u[6] = f2bf(hi.z); r.u[7] = f2bf(hi.w);
  return r.v;
}

// Kernel 1: norms + min-array init (+ optional fp32->bf16 conversion).
template <bool CONV>
__global__ __launch_bounds__(256) void prep_kernel(
    const float* __restrict__ pred, const float* __restrict__ label,
    unsigned short* __restrict__ predbf, unsigned short* __restrict__ labelbf,
    float* __restrict__ x2, float* __restrict__ y2,
    unsigned* __restrict__ minN, unsigned* __restrict__ minM) {
  int t = threadIdx.x;
  int lane = t & 15;
  long row = (long)blockIdx.x * 16 + (t >> 4);
  const float4* src;
  unsigned short* bdst;
  float* ndst;
  unsigned* mdst;
  if (row < BNT) {
    src = (const float4*)(pred + row * D_);
    bdst = predbf + row * D_;
    ndst = x2 + row;
    mdst = minN + row;
  } else {
    long r2 = row - BNT;
    src = (const float4*)(label + r2 * D_);
    bdst = labelbf + r2 * D_;
    ndst = y2 + r2;
    mdst = minM + r2;
  }
  float4 v = src[lane];
  if (CONV) {
    ushort4 p;
    p.x = f2bf(v.x); p.y = f2bf(v.y); p.z = f2bf(v.z); p.w = f2bf(v.w);
    *(ushort4*)(bdst + lane * 4) = p;
  }
  float s = v.x * v.x + v.y * v.y + v.z * v.z + v.w * v.w;
  s += __shfl_xor(s, 1);
  s += __shfl_xor(s, 2);
  s += __shfl_xor(s, 4);
  s += __shfl_xor(s, 8);
  if (lane == 0) {
    *ndst = s;
    *mdst = 0xFFFFFFFFu;  // +inf key
  }
}

// Kernel 2 (single fused pass, NO in-loop barriers / atomics / LDS staging):
// block = 4 waves, owns a 64-row A-band (registers, 4x redundant per wave) and
// streams a 1024-row B-chunk with fragments loaded global->register directly
// (waves partition B-rows, so there is no cross-wave reuse of B).
//   minN[n]: rmin regs across chunk -> shfl + cross-wave LDS combine -> atomic
//   minM[m]: per-iter in-wave reduce -> cmLDS (plain store) -> batch atomics
template <bool BF>
__global__ __launch_bounds__(256) void fused_kernel(
    const void* __restrict__ Asrc, const void* __restrict__ Bsrc,
    const float* __restrict__ x2g, const float* __restrict__ y2g,
    unsigned* __restrict__ minN, unsigned* __restrict__ minM) {
  __shared__ float cmLDS[CHUNK_B];
  __shared__ float red[4][TA];

  const int t = threadIdx.x;
  const int b = blockIdx.z;
  const int a0 = blockIdx.x * TA;
  const int row0 = blockIdx.y * CHUNK_B;  // chunk base in B rows
  const int w = t >> 6, l = t & 63;
  const int g = l >> 4, c = l & 15;

  // ---- A fragments: direct global -> registers (shared band, L2-hot) ----
  bf16x8 af[2][4];
  if (BF) {
    const unsigned short* Ab =
        (const unsigned short*)Asrc + ((size_t)b * N_ + a0) * D_;
#pragma unroll
    for (int kk = 0; kk < 2; kk++)
#pragma unroll
      for (int mi = 0; mi < 4; mi++)
        af[kk][mi] = *(const bf16x8*)(Ab + (mi * 16 + c) * D_ + kk * 32 + g * 8);
  } else {
    const float* Af = (const float*)Asrc + ((size_t)b * N_ + a0) * D_;
#pragma unroll
    for (int kk = 0; kk < 2; kk++)
#pragma unroll
      for (int mi = 0; mi < 4; mi++) {
        const float4* p =
            (const float4*)(Af + (mi * 16 + c) * D_ + kk * 32 + g * 8);
        af[kk][mi] = cvt8(p[0], p[1]);
      }
  }

  // x2 by output A-row (constant over the chunk loop).
  float x2v[4][4];
#pragma unroll
  for (int mi = 0; mi < 4; mi++)
#pragma unroll
    for (int e = 0; e < 4; e++)
      x2v[mi][e] = x2g[(size_t)b * N_ + a0 + mi * 16 + g * 4 + e];

  float rmin[4][4];
#pragma unroll
  for (int mi = 0; mi < 4; mi++)
#pragma unroll
    for (int e = 0; e < 4; e++) rmin[mi][e] = INFINITY;

  const unsigned short* Bb = (const unsigned short*)Bsrc + ((size_t)b * M_ + row0) * D_;
  const float* Bf = (const float*)Bsrc + ((size_t)b * M_ + row0) * D_;
  const float* yb = y2g + (size_t)b * M_ + row0;

#pragma unroll 4
  for (int it = 0; it < CHUNK_TILES; it++) {
    const int r = it * TB + w * 16 + c;  // this lane's B row within chunk
    float nbv = yb[r];
    bf16x8 b0, b1;
    if (BF) {
      b0 = *(const bf16x8*)(Bb + (size_t)r * D_ + g * 8);
      b1 = *(const bf16x8*)(Bb + (size_t)r * D_ + 32 + g * 8);
    } else {
      const float4* p0 = (const float4*)(Bf + (size_t)r * D_ + g * 8);
      const float4* p1 = (const float4*)(Bf + (size_t)r * D_ + 32 + g * 8);
      b0 = cvt8(p0[0], p0[1]);
      b1 = cvt8(p1[0], p1[1]);
    }

    f32x4 acc[4];
#pragma unroll
    for (int mi = 0; mi < 4; mi++)
      acc[mi] = __builtin_amdgcn_mfma_f32_16x16x32_bf16(
          af[0][mi], b0, (f32x4){0.f, 0.f, 0.f, 0.f}, 0, 0, 0);
#pragma unroll
    for (int mi = 0; mi < 4; mi++)
      acc[mi] = __builtin_amdgcn_mfma_f32_16x16x32_bf16(
          af[1][mi], b1, acc[mi], 0, 0, 0);

    float cm = INFINITY;
#pragma unroll
    for (int mi = 0; mi < 4; mi++)
#pragma unroll
      for (int e = 0; e < 4; e++) {
        rmin[mi][e] = fminf(rmin[mi][e], fmaf(-2.f, acc[mi][e], nbv));
        cm = fminf(cm, fmaf(-2.f, acc[mi][e], x2v[mi][e]));
      }
    cm = fminf(cm, __shfl_xor(cm, 16));
    cm = fminf(cm, __shfl_xor(cm, 32));
    if (g == 0) cmLDS[r] = cm;  // plain LDS store, no atomic, no barrier
  }

  // ---- finish: row-min across c-lanes, then across waves via LDS ----
#pragma unroll
  for (int mi = 0; mi < 4; mi++)
#pragma unroll
    for (int e = 0; e < 4; e++) {
      float r = rmin[mi][e];
      r = fminf(r, __shfl_xor(r, 1));
      r = fminf(r, __shfl_xor(r, 2));
      r = fminf(r, __shfl_xor(r, 4));
      r = fminf(r, __shfl_xor(r, 8));
      rmin[mi][e] = r;
    }
  if (c == 0) {
#pragma unroll
    for (int mi = 0; mi < 4; mi++)
#pragma unroll
      for (int e = 0; e < 4; e++)
        red[w][mi * 16 + g * 4 + e] = rmin[mi][e];
  }
  __syncthreads();
  if (t < TA) {
    float m = fminf(fminf(red[0][t], red[1][t]), fminf(red[2][t], red[3][t]));
    atomicMin(&minN[(size_t)b * N_ + a0 + t], fkey(m));
  }
  // col-min flush: one atomic per B-row of the chunk (4 per thread)
#pragma unroll
  for (int i = 0; i < CHUNK_B / 256; i++) {
    int r = i * 256 + t;
    atomicMin(&minM[(size_t)b * M_ + row0 + r], fkey(cmLDS[r]));
  }
}

// Kernel 3 (single block): waves 0-7 reduce dir0, waves 8-15 dir1; sqrt+sum.
__global__ __launch_bounds__(1024) void final_kernel(
    const unsigned* __restrict__ minN, const unsigned* __restrict__ minM,
    const float* __restrict__ x2, const float* __restrict__ y2,
    float* __restrict__ out) {
  int t = threadIdx.x;
  int dir = t >> 9;
  int i0 = t & 511;
  const unsigned* src = dir ? minM : minN;
  const float* nrm = dir ? y2 : x2;
  float mx = -INFINITY;
  for (int i = i0; i < BNT / 4; i += 512) {
    uint4 k = ((const uint4*)src)[i];
    float4 nv = ((const float4*)nrm)[i];
    mx = fmaxf(mx, nv.x + funkey(k.x));
    mx = fmaxf(mx, nv.y + funkey(k.y));
    mx = fmaxf(mx, nv.z + funkey(k.z));
    mx = fmaxf(mx, nv.w + funkey(k.w));
  }
#pragma unroll
  for (int mask = 1; mask < 64; mask <<= 1) mx = fmaxf(mx, __shfl_xor(mx, mask));
  __shared__ float sm[16];
  if ((t & 63) == 0) sm[t >> 6] = mx;
  __syncthreads();
  if (t == 0) {
    float a = -INFINITY, bm = -INFINITY;
#pragma unroll
    for (int i = 0; i < 8; i++) {
      a = fmaxf(a, sm[i]);
      bm = fmaxf(bm, sm[8 + i]);
    }
    out[0] = sqrtf(fmaxf(a, 1e-12f)) + sqrtf(fmaxf(bm, 1e-12f));
  }
}

extern "C" void kernel_launch(void* const* d_in, const int* in_sizes, int n_in,
                              void* d_out, int out_size, void* d_ws, size_t ws_size,
                              hipStream_t stream) {
  const float* pred = (const float*)d_in[0];
  const float* label = (const float*)d_in[1];
  char* ws = (char*)d_ws;

  const size_t bfBytes = (size_t)BNT * D_ * 2;  // 4 MB per array
  const size_t needFast = 2 * bfBytes + (size_t)(BNT + BMT) * 8 + 64;

  if (ws_size >= needFast) {
    unsigned short* predbf = (unsigned short*)ws;
    unsigned short* labelbf = (unsigned short*)(ws + bfBytes);
    float* x2 = (float*)(ws + 2 * bfBytes);
    float* y2 = x2 + BNT;
    unsigned* minN = (unsigned*)(y2 + BMT);
    unsigned* minM = minN + BNT;

    prep_kernel<true><<<(BNT + BMT) / 16, 256, 0, stream>>>(
        pred, label, predbf, labelbf, x2, y2, minN, minM);
    fused_kernel<true><<<dim3(N_ / TA, MCHUNK, B_), 256, 0, stream>>>(
        predbf, labelbf, x2, y2, minN, minM);
    final_kernel<<<1, 1024, 0, stream>>>(minN, minM, x2, y2, (float*)d_out);
  } else {
    float* x2 = (float*)ws;
    float* y2 = x2 + BNT;
    unsigned* minN = (unsigned*)(y2 + BMT);
    unsigned* minM = minN + BNT;

    prep_kernel<false><<<(BNT + BMT) / 16, 256, 0, stream>>>(
        pred, label, nullptr, nullptr, x2, y2, minN, minM);
    fused_kernel<false><<<dim3(N_ / TA, MCHUNK, B_), 256, 0, stream>>>(
        pred, label, x2, y2, minN, minM);
    final_kernel<<<1, 1024, 0, stream>>>(minN, minM, x2, y2, (float*)d_out);
  }
}